// Round 22
// baseline (108.568 us; speedup 1.0000x reference)
//
#include <hip/hip_runtime.h>
#include <hip/hip_bf16.h>

// PartitionedNormalization: per-domain BN stats (training mode) + affine.
// out[B][128] f32 = (gg+dg[s])*(x-mean[s])*rsqrt(var[s]+eps) + (gb+db[s])
//
// R22 = R21 resubmitted (container died before benching).
// Producer/consumer pass 1: stage 64-row chunk to LDS (write-once), wave w
// consumes ONLY domains {2w,2w+1} into register accumulators (read-once,
// no RMW chains, no atomics; domains disjoint across waves so the flush
// needs no combine). 32KB LDS -> 4 blocks/CU = 16 waves/CU.

#define DIM 128
#define NDOM 8
#define PENT (NDOM + 2 * NDOM * DIM)  // 8 counts + 1024 sums + 1024 sqsums = 2056
#define EPSV 1e-3f
#define CHUNK 64  // rows staged per round (64 x 512B = 32KB)

// ---------------- pass 1: stage-then-consume, register accumulation ----------------
__global__ __launch_bounds__(256) void pn_reduce(const float4* __restrict__ x4,
                                                 const int* __restrict__ seg,
                                                 float* __restrict__ partials,
                                                 int rowsPerBlock) {
  __shared__ float4 buf[CHUNK * 32];  // [row][c4], 32 KB
  __shared__ int lseg[CHUNK];
  const int tid = threadIdx.x;
  const int w = tid >> 6;  // wave 0..3 -> owns domains 2w, 2w+1
  const int l = tid & 63;  // lane; covers cols 2l, 2l+1
  const int row0blk = blockIdx.x * rowsPerBlock;

  float2 sum0 = make_float2(0.f, 0.f), sum1 = make_float2(0.f, 0.f);
  float2 sq0 = make_float2(0.f, 0.f), sq1 = make_float2(0.f, 0.f);
  float cnt0 = 0.f, cnt1 = 0.f;

  for (int c0 = 0; c0 < rowsPerBlock; c0 += CHUNK) {
    // ---- phase A: cooperative stage (coalesced float4, write-once) ----
    const int base4 = (row0blk + c0) * 32;  // float4 index of chunk start
#pragma unroll
    for (int i = 0; i < 8; ++i) buf[tid + i * 256] = x4[base4 + tid + i * 256];
    if (tid < CHUNK) lseg[tid] = seg[row0blk + c0 + tid];
    __syncthreads();

    // ---- phase B: wave w consumes rows of its two domains (read-once) ----
    for (int r = 0; r < CHUNK; ++r) {
      const int s = lseg[r];  // wave-uniform (LDS broadcast)
      if ((s >> 1) == w) {
        const float2 v =
            *(const float2*)((const float*)(buf + r * 32) + 2 * l);
        if (s & 1) {
          sum1.x += v.x;
          sum1.y += v.y;
          sq1.x = fmaf(v.x, v.x, sq1.x);
          sq1.y = fmaf(v.y, v.y, sq1.y);
          cnt1 += 1.f;
        } else {
          sum0.x += v.x;
          sum0.y += v.y;
          sq0.x = fmaf(v.x, v.x, sq0.x);
          sq0.y = fmaf(v.y, v.y, sq0.y);
          cnt0 += 1.f;
        }
      }
    }
    __syncthreads();  // protect buf before next stage
  }

  // ---- flush: wave w exclusively owns domains 2w,2w+1 -> direct writes ----
  const int d0 = 2 * w, d1 = 2 * w + 1;
  float* outp = partials + (size_t)blockIdx.x * PENT;
  if (l == 0) {
    outp[d0] = cnt0;
    outp[d1] = cnt1;
  }
  float* ps = outp + NDOM;
  ps[d0 * DIM + 2 * l] = sum0.x;
  ps[d0 * DIM + 2 * l + 1] = sum0.y;
  ps[d1 * DIM + 2 * l] = sum1.x;
  ps[d1 * DIM + 2 * l + 1] = sum1.y;
  float* pq = ps + NDOM * DIM;
  pq[d0 * DIM + 2 * l] = sq0.x;
  pq[d0 * DIM + 2 * l + 1] = sq0.y;
  pq[d1 * DIM + 2 * l] = sq1.x;
  pq[d1 * DIM + 2 * l + 1] = sq1.y;
}

// ---------------- pass 2a: reduce NB partial rows -> 64 ----------------
__global__ __launch_bounds__(256) void pn_reduce2(const float* __restrict__ partials,
                                                  float* __restrict__ partials2,
                                                  int NB) {
  const int b = blockIdx.x;  // 0..63
  const int per = NB >> 6;
  const int b0 = b * per;
  const int tid = threadIdx.x;
  float acc[9];
#pragma unroll
  for (int i = 0; i < 9; ++i) acc[i] = 0.f;
  for (int j = b0; j < b0 + per; ++j) {
    const float* p = partials + (size_t)j * PENT;
#pragma unroll
    for (int i = 0; i < 9; ++i) {
      const int e = tid + i * 256;
      if (e < PENT) acc[i] += p[e];
    }
  }
  float* o = partials2 + (size_t)b * PENT;
#pragma unroll
  for (int i = 0; i < 9; ++i) {
    const int e = tid + i * 256;
    if (e < PENT) o[e] = acc[i];
  }
}

// ---------------- pass 2b: final reduce + scale/shift table (4 blocks) ----------------
__global__ __launch_bounds__(256) void pn_finalize(const float* __restrict__ partials2,
                                                   const float* __restrict__ gg,
                                                   const float* __restrict__ gb,
                                                   const float* __restrict__ dg,
                                                   const float* __restrict__ db,
                                                   float* __restrict__ stats) {
  const int t = blockIdx.x * 256 + threadIdx.x;  // (k = t>>7, d = t&127)
  const int k = t >> 7;
  const int d = t & (DIM - 1);
  float c = 0.f, s = 0.f, q = 0.f;
  for (int j = 0; j < 64; ++j) {
    const float* p = partials2 + (size_t)j * PENT;
    c += p[k];
    s += p[NDOM + t];
    q += p[NDOM + NDOM * DIM + t];
  }
  const float n = fmaxf(c, 1.f);
  const float mean = s / n;
  const float var = fmaxf(q / n - mean * mean, 0.f);
  const float rstd = rsqrtf(var + EPSV);
  const float scale = (gg[d] + dg[t]) * rstd;  // dg[k*128+d] == dg[t]
  const float shift = (gb[d] + db[t]) - scale * mean;
  stats[t] = scale;
  stats[NDOM * DIM + t] = shift;
}

// ---------------- pass 3: normalize (one-shot, 1 float4/thread) ----------------
__global__ __launch_bounds__(256) void pn_apply(const float* __restrict__ x,
                                                const int* __restrict__ seg,
                                                const float* __restrict__ stats,
                                                float* __restrict__ out) {
  const int g = blockIdx.x * 256 + threadIdx.x;  // float4 index
  const int row = g >> 5;                        // 32 float4 per row
  const int c4 = g & 31;
  const int s = seg[row];
  const float4 xv = ((const float4*)x)[g];
  const float4 a = ((const float4*)(stats + s * DIM))[c4];
  const float4 b = ((const float4*)(stats + NDOM * DIM + s * DIM))[c4];
  float4 o;
  o.x = fmaf(xv.x, a.x, b.x);
  o.y = fmaf(xv.y, a.y, b.y);
  o.z = fmaf(xv.z, a.z, b.z);
  o.w = fmaf(xv.w, a.w, b.w);
  ((float4*)out)[g] = o;
}

extern "C" void kernel_launch(void* const* d_in, const int* in_sizes, int n_in,
                              void* d_out, int out_size, void* d_ws, size_t ws_size,
                              hipStream_t stream) {
  const float* x = (const float*)d_in[0];
  const float* gg = (const float*)d_in[1];
  const float* gb = (const float*)d_in[2];
  const float* dg = (const float*)d_in[3];
  const float* db = (const float*)d_in[4];
  const int* seg = (const int*)d_in[5];
  float* out = (float*)d_out;
  const int B = in_sizes[5];  // 262144

  // workspace: partials[NB][PENT] | partials2[64][PENT] | stats[2048]
  const int NB = 1024;  // 4 blocks/CU (32.3KB LDS), exactly one round
  float* partials = (float*)d_ws;
  float* partials2 = partials + (size_t)NB * PENT;
  float* stats = partials2 + (size_t)64 * PENT;

  const int rpb = B / NB;  // 256 rows/block = 4 chunks of 64

  pn_reduce<<<NB, 256, 0, stream>>>((const float4*)x, seg, partials, rpb);
  pn_reduce2<<<64, 256, 0, stream>>>(partials, partials2, NB);
  pn_finalize<<<4, 256, 0, stream>>>(partials2, gg, gb, dg, db, stats);

  const int nblk = (B * (DIM / 4)) / 256;  // 32768
  pn_apply<<<nblk, 256, 0, stream>>>(x, seg, stats, out);
}